// Round 2
// baseline (31.914 us; speedup 1.0000x reference)
//
#include <hip/hip_runtime.h>
#include <math.h>

namespace {
constexpr int Nn = 4, Hh = 256, Ww = 256;
constexpr int HW = Hh * Ww;
constexpr int P  = Nn * HW;          // 262144 pixels
constexpr int Fn = 13776;
constexpr float ZFAR  = 100.0f;
constexpr float ZNEAR = 1.0f;
constexpr float INV_SIG = 1.0f / (1e-4f + 1e-8f);   // 1/(SIGMA+1e-8)
constexpr float INV_GAM = 1.0f / 1e-4f;             // 1/GAMMA
constexpr float EPSF    = 1e-10f;
constexpr float INV_ZR  = 1.0f / (ZFAR - ZNEAR);
constexpr size_t FA_BYTES = (size_t)Fn * 48 * sizeof(float);  // 2.64 MB
}

#define FMA4(A, C, Rp, i)                                   \
    {                                                       \
        float4 _t = (Rp)[i];                                \
        A.x = fmaf((C), _t.x, A.x);                         \
        A.y = fmaf((C), _t.y, A.y);                         \
        A.z = fmaf((C), _t.z, A.z);                         \
        A.w = fmaf((C), _t.w, A.w);                         \
    }

// ---- prep: flatten vf[faces] into (F, 3, 16) so the pixel gather is one-level ----
__global__ __launch_bounds__(256) void build_face_attrs(
    const float* __restrict__ vf, const int* __restrict__ faces,
    float* __restrict__ fa)
{
    const int f = blockIdx.x * blockDim.x + threadIdx.x;
    if (f >= Fn) return;
    const int v0 = faces[3 * f + 0];
    const int v1 = faces[3 * f + 1];
    const int v2 = faces[3 * f + 2];
    float4* dst = reinterpret_cast<float4*>(fa + (size_t)f * 48);
    const float4* s0 = reinterpret_cast<const float4*>(vf + (size_t)v0 * 16);
    const float4* s1 = reinterpret_cast<const float4*>(vf + (size_t)v1 * 16);
    const float4* s2 = reinterpret_cast<const float4*>(vf + (size_t)v2 * 16);
    dst[0] = s0[0]; dst[1]  = s0[1]; dst[2]  = s0[2]; dst[3]  = s0[3];
    dst[4] = s1[0]; dst[5]  = s1[1]; dst[6]  = s1[2]; dst[7]  = s1[3];
    dst[8] = s2[0]; dst[9]  = s2[1]; dst[10] = s2[2]; dst[11] = s2[3];
}

template <bool USE_FA>
__global__ __launch_bounds__(256) void render_kernel(
    const float* __restrict__ vf,     // (V,16)
    const float* __restrict__ bary,   // (P,8,3)
    const float* __restrict__ dists,  // (P,8)
    const float* __restrict__ zbuf,   // (P,8)
    const int*  __restrict__ faces,   // (F,3)
    const int*  __restrict__ p2f,     // (P,8)
    const float* __restrict__ fa,     // (F,3,16) flattened, or nullptr
    float* __restrict__ out)          // (N,17,H,W)
{
    const int p = blockIdx.x * blockDim.x + threadIdx.x;
    if (p >= P) return;

    // ---- vectorized per-pixel loads ----
    const int4* fp = reinterpret_cast<const int4*>(p2f + (size_t)p * 8);
    int4 fa_ = fp[0], fb_ = fp[1];
    int fk[8] = {fa_.x, fa_.y, fa_.z, fa_.w, fb_.x, fb_.y, fb_.z, fb_.w};

    const float4* dp = reinterpret_cast<const float4*>(dists + (size_t)p * 8);
    float4 da = dp[0], db = dp[1];
    float dk[8] = {da.x, da.y, da.z, da.w, db.x, db.y, db.z, db.w};

    const float4* zp = reinterpret_cast<const float4*>(zbuf + (size_t)p * 8);
    float4 za = zp[0], zb = zp[1];
    float zk[8] = {za.x, za.y, za.z, za.w, zb.x, zb.y, zb.z, zb.w};

    const float4* bp = reinterpret_cast<const float4*>(bary + (size_t)p * 24);
    float4 b0 = bp[0], b1 = bp[1], b2 = bp[2], b3 = bp[3], b4 = bp[4], b5 = bp[5];
    float bc[24] = {b0.x, b0.y, b0.z, b0.w,
                    b1.x, b1.y, b1.z, b1.w,
                    b2.x, b2.y, b2.z, b2.w,
                    b3.x, b3.y, b3.z, b3.w,
                    b4.x, b4.y, b4.z, b4.w,
                    b5.x, b5.y, b5.z, b5.w};

    // ---- pass 1: prob (sigmoid), z_inv, alpha product, z_max ----
    float prob[8], zi[8];
    float keep = 1.0f;     // prod(1 - prob)
    float zmax = EPSF;     // clip(max(z_inv), EPS)
#pragma unroll
    for (int k = 0; k < 8; ++k) {
        const bool valid = fk[k] >= 0;
        float pr = valid ? 1.0f / (1.0f + __expf(dk[k] * INV_SIG)) : 0.0f;
        prob[k] = pr;
        keep *= (1.0f - pr);
        float zv = valid ? (ZFAR - zk[k]) * INV_ZR : 0.0f;
        zi[k] = zv;
        zmax = fmaxf(zmax, zv);
    }

    // ---- pass 2: softmax weights + running-best select (no runtime indexing) ----
    const float delta = fmaxf(__expf((EPSF - zmax) * INV_GAM), EPSF);
    float denom = delta;
    float wk_[8];
    float wbest = 0.0f, cb0 = 0.0f, cb1 = 0.0f, cb2 = 0.0f;
    int   fbest = 0, kbest = -1, nnz = 0;
#pragma unroll
    for (int k = 0; k < 8; ++k) {
        float wv = prob[k] * __expf((zi[k] - zmax) * INV_GAM);
        wk_[k] = wv;
        denom += wv;
        nnz += (wv != 0.0f) ? 1 : 0;
        const bool better = wv > wbest;
        wbest = better ? wv : wbest;
        fbest = better ? fk[k] : fbest;
        kbest = better ? k : kbest;
        cb0 = better ? bc[k * 3 + 0] : cb0;
        cb1 = better ? bc[k * 3 + 1] : cb1;
        cb2 = better ? bc[k * 3 + 2] : cb2;
    }

    // ---- fast path: one dense single-level gather for the dominant sample ----
    float4 acc0 = make_float4(0.f, 0.f, 0.f, 0.f);
    float4 acc1 = make_float4(0.f, 0.f, 0.f, 0.f);
    float4 acc2 = make_float4(0.f, 0.f, 0.f, 0.f);
    float4 acc3 = make_float4(0.f, 0.f, 0.f, 0.f);
    if (wbest > 0.0f) {
        const float c0 = wbest * cb0, c1 = wbest * cb1, c2 = wbest * cb2;
        if (USE_FA) {
            const float4* r = reinterpret_cast<const float4*>(fa + (size_t)fbest * 48);
            FMA4(acc0, c0, r, 0); FMA4(acc1, c0, r, 1);
            FMA4(acc2, c0, r, 2); FMA4(acc3, c0, r, 3);
            FMA4(acc0, c1, r, 4); FMA4(acc1, c1, r, 5);
            FMA4(acc2, c1, r, 6); FMA4(acc3, c1, r, 7);
            FMA4(acc0, c2, r, 8); FMA4(acc1, c2, r, 9);
            FMA4(acc2, c2, r, 10); FMA4(acc3, c2, r, 11);
        } else {
            const int v0 = faces[fbest * 3 + 0];
            const int v1 = faces[fbest * 3 + 1];
            const int v2 = faces[fbest * 3 + 2];
            const float4* r0 = reinterpret_cast<const float4*>(vf + (size_t)v0 * 16);
            const float4* r1 = reinterpret_cast<const float4*>(vf + (size_t)v1 * 16);
            const float4* r2 = reinterpret_cast<const float4*>(vf + (size_t)v2 * 16);
            FMA4(acc0, c0, r0, 0); FMA4(acc1, c0, r0, 1);
            FMA4(acc2, c0, r0, 2); FMA4(acc3, c0, r0, 3);
            FMA4(acc0, c1, r1, 0); FMA4(acc1, c1, r1, 1);
            FMA4(acc2, c1, r1, 2); FMA4(acc3, c1, r1, 3);
            FMA4(acc0, c2, r2, 0); FMA4(acc1, c2, r2, 1);
            FMA4(acc2, c2, r2, 2); FMA4(acc3, c2, r2, 3);
        }
    }

    // ---- rare path: any other surviving samples (wave-uniform skip) ----
    if (__any(nnz > 1)) {
#pragma unroll
        for (int k = 0; k < 8; ++k) {
            const float wv = wk_[k];
            if (wv != 0.0f && k != kbest) {
                const int f = fk[k];
                const float c0 = wv * bc[k * 3 + 0];
                const float c1 = wv * bc[k * 3 + 1];
                const float c2 = wv * bc[k * 3 + 2];
                if (USE_FA) {
                    const float4* r = reinterpret_cast<const float4*>(fa + (size_t)f * 48);
                    FMA4(acc0, c0, r, 0); FMA4(acc1, c0, r, 1);
                    FMA4(acc2, c0, r, 2); FMA4(acc3, c0, r, 3);
                    FMA4(acc0, c1, r, 4); FMA4(acc1, c1, r, 5);
                    FMA4(acc2, c1, r, 6); FMA4(acc3, c1, r, 7);
                    FMA4(acc0, c2, r, 8); FMA4(acc1, c2, r, 9);
                    FMA4(acc2, c2, r, 10); FMA4(acc3, c2, r, 11);
                } else {
                    const int v0 = faces[f * 3 + 0];
                    const int v1 = faces[f * 3 + 1];
                    const int v2 = faces[f * 3 + 2];
                    const float4* r0 = reinterpret_cast<const float4*>(vf + (size_t)v0 * 16);
                    const float4* r1 = reinterpret_cast<const float4*>(vf + (size_t)v1 * 16);
                    const float4* r2 = reinterpret_cast<const float4*>(vf + (size_t)v2 * 16);
                    FMA4(acc0, c0, r0, 0); FMA4(acc1, c0, r0, 1);
                    FMA4(acc2, c0, r0, 2); FMA4(acc3, c0, r0, 3);
                    FMA4(acc0, c1, r1, 0); FMA4(acc1, c1, r1, 1);
                    FMA4(acc2, c1, r1, 2); FMA4(acc3, c1, r1, 3);
                    FMA4(acc0, c2, r2, 0); FMA4(acc1, c2, r2, 1);
                    FMA4(acc2, c2, r2, 2); FMA4(acc3, c2, r2, 3);
                }
            }
        }
    }

    // ---- epilogue: divide by denom, store channel-major ----
    const float invden = 1.0f / denom;
    const int n  = p / HW;
    const int hw = p - n * HW;
    float* o = out + (size_t)n * 17 * HW + hw;
    o[(size_t)0  * HW] = acc0.x * invden;
    o[(size_t)1  * HW] = acc0.y * invden;
    o[(size_t)2  * HW] = acc0.z * invden;
    o[(size_t)3  * HW] = acc0.w * invden;
    o[(size_t)4  * HW] = acc1.x * invden;
    o[(size_t)5  * HW] = acc1.y * invden;
    o[(size_t)6  * HW] = acc1.z * invden;
    o[(size_t)7  * HW] = acc1.w * invden;
    o[(size_t)8  * HW] = acc2.x * invden;
    o[(size_t)9  * HW] = acc2.y * invden;
    o[(size_t)10 * HW] = acc2.z * invden;
    o[(size_t)11 * HW] = acc2.w * invden;
    o[(size_t)12 * HW] = acc3.x * invden;
    o[(size_t)13 * HW] = acc3.y * invden;
    o[(size_t)14 * HW] = acc3.z * invden;
    o[(size_t)15 * HW] = acc3.w * invden;
    o[(size_t)16 * HW] = 1.0f - keep;   // alpha
}

extern "C" void kernel_launch(void* const* d_in, const int* in_sizes, int n_in,
                              void* d_out, int out_size, void* d_ws, size_t ws_size,
                              hipStream_t stream) {
    const float* vf    = (const float*)d_in[0];
    const float* bary  = (const float*)d_in[1];
    const float* dists = (const float*)d_in[2];
    const float* zbuf  = (const float*)d_in[3];
    const int*   faces = (const int*)d_in[4];
    const int*   p2f   = (const int*)d_in[5];
    float* out = (float*)d_out;

    if (ws_size >= FA_BYTES) {
        float* fa = (float*)d_ws;
        build_face_attrs<<<dim3((Fn + 255) / 256), dim3(256), 0, stream>>>(vf, faces, fa);
        render_kernel<true><<<dim3(P / 256), dim3(256), 0, stream>>>(
            vf, bary, dists, zbuf, faces, p2f, fa, out);
    } else {
        render_kernel<false><<<dim3(P / 256), dim3(256), 0, stream>>>(
            vf, bary, dists, zbuf, faces, p2f, nullptr, out);
    }
}

// Round 3
// 26.568 us; speedup vs baseline: 1.2012x; 1.2012x over previous
//
#include <hip/hip_runtime.h>
#include <math.h>

namespace {
constexpr int Nn = 4, Hh = 256, Ww = 256;
constexpr int HW = Hh * Ww;
constexpr int P  = Nn * HW;          // 262144 pixels
constexpr float ZFAR  = 100.0f;
constexpr float ZNEAR = 1.0f;
constexpr float INV_SIG = 1.0f / (1e-4f + 1e-8f);   // 1/(SIGMA+1e-8)
constexpr float INV_GAM = 1.0f / 1e-4f;             // 1/GAMMA
constexpr float EPSF    = 1e-10f;
constexpr float INV_ZR  = 1.0f / (ZFAR - ZNEAR);
}

#define FMA4(A, C, Rp, i)                                   \
    {                                                       \
        float4 _t = (Rp)[i];                                \
        A.x = fmaf((C), _t.x, A.x);                         \
        A.y = fmaf((C), _t.y, A.y);                         \
        A.z = fmaf((C), _t.z, A.z);                         \
        A.w = fmaf((C), _t.w, A.w);                         \
    }

__global__ __launch_bounds__(256) void render_kernel(
    const float* __restrict__ vf,     // (V,16)
    const float* __restrict__ bary,   // (P,8,3)
    const float* __restrict__ dists,  // (P,8)
    const float* __restrict__ zbuf,   // (P,8)
    const int*  __restrict__ faces,   // (F,3)
    const int*  __restrict__ p2f,     // (P,8)
    float* __restrict__ out)          // (N,17,H,W)
{
    const int p = blockIdx.x * blockDim.x + threadIdx.x;
    if (p >= P) return;

    // ---- loop A: faces + depth only; minimal persistent state ----
    const int4* fp = reinterpret_cast<const int4*>(p2f + (size_t)p * 8);
    int4 fa = fp[0], fb = fp[1];
    int fk[8] = {fa.x, fa.y, fa.z, fa.w, fb.x, fb.y, fb.z, fb.w};

    const float4* zp = reinterpret_cast<const float4*>(zbuf + (size_t)p * 8);
    float4 za = zp[0], zb = zp[1];
    float zraw[8] = {za.x, za.y, za.z, za.w, zb.x, zb.y, zb.z, zb.w};

    float zi[8];
    float zmax = EPSF;
#pragma unroll
    for (int k = 0; k < 8; ++k) {
        const bool valid = fk[k] >= 0;
        float zv = valid ? (ZFAR - zraw[k]) * INV_ZR : 0.0f;
        zi[k] = zv;
        zmax = fmaxf(zmax, zv);
    }

    // ---- loop B: dists consumed immediately; gather predicated per-k ----
    const float4* dp = reinterpret_cast<const float4*>(dists + (size_t)p * 8);
    float4 da = dp[0], db = dp[1];
    float dk[8] = {da.x, da.y, da.z, da.w, db.x, db.y, db.z, db.w};

    const float delta = fmaxf(__expf((EPSF - zmax) * INV_GAM), EPSF);
    float denom = delta;
    float keep  = 1.0f;

    float4 acc0 = make_float4(0.f, 0.f, 0.f, 0.f);
    float4 acc1 = make_float4(0.f, 0.f, 0.f, 0.f);
    float4 acc2 = make_float4(0.f, 0.f, 0.f, 0.f);
    float4 acc3 = make_float4(0.f, 0.f, 0.f, 0.f);

    const float* bpx = bary + (size_t)p * 24;   // lazy bary base

#pragma unroll
    for (int k = 0; k < 8; ++k) {
        const bool valid = fk[k] >= 0;
        // sigmoid(-d/sigma) = 1/(1+exp(d/sigma))
        float pr = valid ? 1.0f / (1.0f + __expf(dk[k] * INV_SIG)) : 0.0f;
        keep *= (1.0f - pr);
        float wv = pr * __expf((zi[k] - zmax) * INV_GAM);
        denom += wv;
        if (wv > 0.0f) {
            const int f  = fk[k];
            const int v0 = faces[f * 3 + 0];
            const int v1 = faces[f * 3 + 1];
            const int v2 = faces[f * 3 + 2];
            const float c0 = wv * bpx[k * 3 + 0];
            const float c1 = wv * bpx[k * 3 + 1];
            const float c2 = wv * bpx[k * 3 + 2];
            const float4* r0 = reinterpret_cast<const float4*>(vf + (size_t)v0 * 16);
            const float4* r1 = reinterpret_cast<const float4*>(vf + (size_t)v1 * 16);
            const float4* r2 = reinterpret_cast<const float4*>(vf + (size_t)v2 * 16);
            FMA4(acc0, c0, r0, 0); FMA4(acc1, c0, r0, 1);
            FMA4(acc2, c0, r0, 2); FMA4(acc3, c0, r0, 3);
            FMA4(acc0, c1, r1, 0); FMA4(acc1, c1, r1, 1);
            FMA4(acc2, c1, r1, 2); FMA4(acc3, c1, r1, 3);
            FMA4(acc0, c2, r2, 0); FMA4(acc1, c2, r2, 1);
            FMA4(acc2, c2, r2, 2); FMA4(acc3, c2, r2, 3);
        }
    }

    // ---- epilogue: divide by denom, store channel-major ----
    const float invden = 1.0f / denom;
    const int n  = p / HW;
    const int hw = p - n * HW;
    float* o = out + (size_t)n * 17 * HW + hw;
    o[(size_t)0  * HW] = acc0.x * invden;
    o[(size_t)1  * HW] = acc0.y * invden;
    o[(size_t)2  * HW] = acc0.z * invden;
    o[(size_t)3  * HW] = acc0.w * invden;
    o[(size_t)4  * HW] = acc1.x * invden;
    o[(size_t)5  * HW] = acc1.y * invden;
    o[(size_t)6  * HW] = acc1.z * invden;
    o[(size_t)7  * HW] = acc1.w * invden;
    o[(size_t)8  * HW] = acc2.x * invden;
    o[(size_t)9  * HW] = acc2.y * invden;
    o[(size_t)10 * HW] = acc2.z * invden;
    o[(size_t)11 * HW] = acc2.w * invden;
    o[(size_t)12 * HW] = acc3.x * invden;
    o[(size_t)13 * HW] = acc3.y * invden;
    o[(size_t)14 * HW] = acc3.z * invden;
    o[(size_t)15 * HW] = acc3.w * invden;
    o[(size_t)16 * HW] = 1.0f - keep;   // alpha
}

extern "C" void kernel_launch(void* const* d_in, const int* in_sizes, int n_in,
                              void* d_out, int out_size, void* d_ws, size_t ws_size,
                              hipStream_t stream) {
    const float* vf    = (const float*)d_in[0];
    const float* bary  = (const float*)d_in[1];
    const float* dists = (const float*)d_in[2];
    const float* zbuf  = (const float*)d_in[3];
    const int*   faces = (const int*)d_in[4];
    const int*   p2f   = (const int*)d_in[5];
    float* out = (float*)d_out;

    render_kernel<<<dim3(P / 256), dim3(256), 0, stream>>>(
        vf, bary, dists, zbuf, faces, p2f, out);
}